// Round 1
// baseline (467.240 us; speedup 1.0000x reference)
//
#include <hip/hip_runtime.h>

#define N_NODES 100000
#define D 128

// ---------------------------------------------------------------------------
// Kernel 1: WT[k][j] = W[j][k]  (so the fused kernel's k-loop loads are
// coalesced: lanes read consecutive j for fixed k)
// ---------------------------------------------------------------------------
__global__ void transpose_W_kernel(const float* __restrict__ W,
                                   float* __restrict__ WT) {
    int j = blockIdx.x;   // 128 blocks  (output row of W)
    int k = threadIdx.x;  // 128 threads (input dim)
    WT[k * D + j] = W[j * D + k];
}

// ---------------------------------------------------------------------------
// Kernel 2: row_ptr[i] = lower_bound(edge_rows, i), i in [0, N_NODES]
// edge_rows is sorted, so [row_ptr[i], row_ptr[i+1]) is node i's edge range.
// ---------------------------------------------------------------------------
__global__ void build_rowptr_kernel(const int* __restrict__ rows,
                                    int* __restrict__ row_ptr, int n_edges) {
    int i = blockIdx.x * blockDim.x + threadIdx.x;
    if (i > N_NODES) return;
    int lo = 0, hi = n_edges;
    while (lo < hi) {
        int mid = (lo + hi) >> 1;
        if (rows[mid] < i) lo = mid + 1; else hi = mid;
    }
    row_ptr[i] = lo;
}

// ---------------------------------------------------------------------------
// Kernel 3: fused SpMM + linear + bias + relu. One 64-lane wave per node.
// Each lane owns features (2*lane, 2*lane+1) as float2.
//   agg[f]  = sum_e vals[e] * h[cols[e]][f]        (register accumulate)
//   out[j]  = relu( sum_k agg[k] * WT[k][j] + b[j] )
// ---------------------------------------------------------------------------
__global__ __launch_bounds__(64)
void gconv_fused_kernel(const int* __restrict__ cols,
                        const float* __restrict__ vals,
                        const float* __restrict__ h,
                        const float* __restrict__ WT,
                        const float* __restrict__ b,
                        const int* __restrict__ row_ptr,
                        float* __restrict__ out) {
    const int node = blockIdx.x;
    const int lane = threadIdx.x;  // 0..63

    const int start = row_ptr[node];
    const int end   = row_ptr[node + 1];

    float2 acc = make_float2(0.f, 0.f);
    for (int e = start; e < end; ++e) {
        const int   c = cols[e];   // uniform across wave -> scalar load
        const float v = vals[e];
        const float2 hv =
            *reinterpret_cast<const float2*>(h + (size_t)c * D + lane * 2);
        acc.x += v * hv.x;
        acc.y += v * hv.y;
    }

    __shared__ float agg[D];
    agg[lane * 2]     = acc.x;
    agg[lane * 2 + 1] = acc.y;
    __syncthreads();

    float o0 = b[lane * 2];
    float o1 = b[lane * 2 + 1];
#pragma unroll 8
    for (int k = 0; k < D; ++k) {
        const float a = agg[k];  // same addr all lanes -> LDS broadcast
        const float2 w =
            *reinterpret_cast<const float2*>(WT + k * D + lane * 2);
        o0 += a * w.x;
        o1 += a * w.y;
    }

    float2 res;
    res.x = o0 > 0.f ? o0 : 0.f;
    res.y = o1 > 0.f ? o1 : 0.f;
    *reinterpret_cast<float2*>(out + (size_t)node * D + lane * 2) = res;
}

// ---------------------------------------------------------------------------
extern "C" void kernel_launch(void* const* d_in, const int* in_sizes, int n_in,
                              void* d_out, int out_size, void* d_ws,
                              size_t ws_size, hipStream_t stream) {
    const int*   edge_rows = (const int*)d_in[0];
    const int*   edge_cols = (const int*)d_in[1];
    const float* edge_vals = (const float*)d_in[2];
    const float* h         = (const float*)d_in[3];
    const float* W         = (const float*)d_in[4];
    const float* b         = (const float*)d_in[5];
    float*       out       = (float*)d_out;

    const int n_edges = in_sizes[0];

    // workspace layout: [WT: 128*128 f32 = 64KB][row_ptr: N_NODES+1 ints]
    float* WT      = (float*)d_ws;
    int*   row_ptr = (int*)((char*)d_ws + D * D * sizeof(float));

    transpose_W_kernel<<<D, D, 0, stream>>>(W, WT);

    const int rp_threads = 256;
    const int rp_blocks  = (N_NODES + 1 + rp_threads - 1) / rp_threads;
    build_rowptr_kernel<<<rp_blocks, rp_threads, 0, stream>>>(edge_rows,
                                                              row_ptr, n_edges);

    gconv_fused_kernel<<<N_NODES, 64, 0, stream>>>(edge_cols, edge_vals, h, WT,
                                                   b, row_ptr, out);
}

// Round 2
// 326.974 us; speedup vs baseline: 1.4290x; 1.4290x over previous
//
#include <hip/hip_runtime.h>

#define N_NODES 100000
#define D 128

// ---------------------------------------------------------------------------
// Kernel 1: WT[k][j] = W[j][k]
// ---------------------------------------------------------------------------
__global__ void transpose_W_kernel(const float* __restrict__ W,
                                   float* __restrict__ WT) {
    int j = blockIdx.x;
    int k = threadIdx.x;
    WT[k * D + j] = W[j * D + k];
}

// ---------------------------------------------------------------------------
// Kernel 2: row_ptr[i] = lower_bound(edge_rows, i)
// ---------------------------------------------------------------------------
__global__ void build_rowptr_kernel(const int* __restrict__ rows,
                                    int* __restrict__ row_ptr, int n_edges) {
    int i = blockIdx.x * blockDim.x + threadIdx.x;
    if (i > N_NODES) return;
    int lo = 0, hi = n_edges;
    while (lo < hi) {
        int mid = (lo + hi) >> 1;
        if (rows[mid] < i) lo = mid + 1; else hi = mid;
    }
    row_ptr[i] = lo;
}

// ---------------------------------------------------------------------------
// Kernel 3: fused SpMM + linear + bias + relu. One 64-lane wave per node.
// Wave split into two 32-lane halves; each half processes alternate edges
// with float4 (16B/lane) row loads, 4 edges in flight per half (8 per wave).
// Halves combined via __shfl_xor(.,32). Linear stage: lane owns features
// 4*fl..4*fl+3; each half covers 64 of the 128 k-steps, combined the same way.
// ---------------------------------------------------------------------------
__global__ __launch_bounds__(64)
void gconv_fused_kernel(const int* __restrict__ cols,
                        const float* __restrict__ vals,
                        const float* __restrict__ h,
                        const float* __restrict__ WT,
                        const float* __restrict__ b,
                        const int* __restrict__ row_ptr,
                        float* __restrict__ out) {
    const int node = blockIdx.x;
    const int lane = threadIdx.x;   // 0..63
    const int half = lane >> 5;     // 0 or 1
    const int fl   = lane & 31;     // lane within half

    const int start = row_ptr[node];
    const int end   = row_ptr[node + 1];

    float4 acc = make_float4(0.f, 0.f, 0.f, 0.f);

    // this half processes edges start+half, start+half+2, ...
    int e = start + half;

    // main loop: 4 edges in flight per half (8 gathers in flight per wave)
    for (; e + 6 < end; e += 8) {
        const int c0 = cols[e];
        const int c1 = cols[e + 2];
        const int c2 = cols[e + 4];
        const int c3 = cols[e + 6];
        const float v0 = vals[e];
        const float v1 = vals[e + 2];
        const float v2 = vals[e + 4];
        const float v3 = vals[e + 6];
        const float4 h0 = *reinterpret_cast<const float4*>(h + (size_t)c0 * D + fl * 4);
        const float4 h1 = *reinterpret_cast<const float4*>(h + (size_t)c1 * D + fl * 4);
        const float4 h2 = *reinterpret_cast<const float4*>(h + (size_t)c2 * D + fl * 4);
        const float4 h3 = *reinterpret_cast<const float4*>(h + (size_t)c3 * D + fl * 4);
        acc.x += v0 * h0.x; acc.y += v0 * h0.y; acc.z += v0 * h0.z; acc.w += v0 * h0.w;
        acc.x += v1 * h1.x; acc.y += v1 * h1.y; acc.z += v1 * h1.z; acc.w += v1 * h1.w;
        acc.x += v2 * h2.x; acc.y += v2 * h2.y; acc.z += v2 * h2.z; acc.w += v2 * h2.w;
        acc.x += v3 * h3.x; acc.y += v3 * h3.y; acc.z += v3 * h3.z; acc.w += v3 * h3.w;
    }
    // tail (at most 3 edges for this half)
    for (; e < end; e += 2) {
        const int   c = cols[e];
        const float v = vals[e];
        const float4 hv = *reinterpret_cast<const float4*>(h + (size_t)c * D + fl * 4);
        acc.x += v * hv.x; acc.y += v * hv.y; acc.z += v * hv.z; acc.w += v * hv.w;
    }

    // combine the two halves (lane l <-> lane l^32)
    acc.x += __shfl_xor(acc.x, 32);
    acc.y += __shfl_xor(acc.y, 32);
    acc.z += __shfl_xor(acc.z, 32);
    acc.w += __shfl_xor(acc.w, 32);

    __shared__ float agg[D];
    if (half == 0) {
        *reinterpret_cast<float4*>(agg + fl * 4) = acc;
    }
    __syncthreads();

    // linear: lane owns j = 4*fl..4*fl+3; this half covers k in [half*64, +64)
    float4 o = make_float4(0.f, 0.f, 0.f, 0.f);
    const int k0 = half * 64;
#pragma unroll 8
    for (int kk = 0; kk < 64; ++kk) {
        const int k = k0 + kk;
        const float a = agg[k];  // broadcast within each half
        const float4 w = *reinterpret_cast<const float4*>(WT + k * D + fl * 4);
        o.x += a * w.x; o.y += a * w.y; o.z += a * w.z; o.w += a * w.w;
    }
    o.x += __shfl_xor(o.x, 32);
    o.y += __shfl_xor(o.y, 32);
    o.z += __shfl_xor(o.z, 32);
    o.w += __shfl_xor(o.w, 32);

    if (half == 0) {
        float4 res;
        const float4 bb = *reinterpret_cast<const float4*>(b + fl * 4);
        res.x = o.x + bb.x; res.y = o.y + bb.y;
        res.z = o.z + bb.z; res.w = o.w + bb.w;
        res.x = res.x > 0.f ? res.x : 0.f;
        res.y = res.y > 0.f ? res.y : 0.f;
        res.z = res.z > 0.f ? res.z : 0.f;
        res.w = res.w > 0.f ? res.w : 0.f;
        *reinterpret_cast<float4*>(out + (size_t)node * D + fl * 4) = res;
    }
}

// ---------------------------------------------------------------------------
extern "C" void kernel_launch(void* const* d_in, const int* in_sizes, int n_in,
                              void* d_out, int out_size, void* d_ws,
                              size_t ws_size, hipStream_t stream) {
    const int*   edge_rows = (const int*)d_in[0];
    const int*   edge_cols = (const int*)d_in[1];
    const float* edge_vals = (const float*)d_in[2];
    const float* h         = (const float*)d_in[3];
    const float* W         = (const float*)d_in[4];
    const float* b         = (const float*)d_in[5];
    float*       out       = (float*)d_out;

    const int n_edges = in_sizes[0];

    float* WT      = (float*)d_ws;
    int*   row_ptr = (int*)((char*)d_ws + D * D * sizeof(float));

    transpose_W_kernel<<<D, D, 0, stream>>>(W, WT);

    const int rp_threads = 256;
    const int rp_blocks  = (N_NODES + 1 + rp_threads - 1) / rp_threads;
    build_rowptr_kernel<<<rp_blocks, rp_threads, 0, stream>>>(edge_rows,
                                                              row_ptr, n_edges);

    gconv_fused_kernel<<<N_NODES, 64, 0, stream>>>(edge_cols, edge_vals, h, WT,
                                                   b, row_ptr, out);
}

// Round 3
// 185.834 us; speedup vs baseline: 2.5143x; 1.7595x over previous
//
#include <hip/hip_runtime.h>
#include <hip/hip_bf16.h>

#define N_NODES 100000
#define D 128
#define GB_NODES 32

// ---------------------------------------------------------------------------
// Kernel 1: WT[k][j] = W[j][k]
// ---------------------------------------------------------------------------
__global__ void transpose_W_kernel(const float* __restrict__ W,
                                   float* __restrict__ WT) {
    int j = blockIdx.x;
    int k = threadIdx.x;
    WT[k * D + j] = W[j * D + k];
}

// ---------------------------------------------------------------------------
// Kernel 2: row_ptr[i] = lower_bound(edge_rows, i)
// ---------------------------------------------------------------------------
__global__ void build_rowptr_kernel(const int* __restrict__ rows,
                                    int* __restrict__ row_ptr, int n_edges) {
    int i = blockIdx.x * blockDim.x + threadIdx.x;
    if (i > N_NODES) return;
    int lo = 0, hi = n_edges;
    while (lo < hi) {
        int mid = (lo + hi) >> 1;
        if (rows[mid] < i) lo = mid + 1; else hi = mid;
    }
    row_ptr[i] = lo;
}

// ---------------------------------------------------------------------------
// Kernel 3: G = H @ W^T, stored bf16. Safe fp32 vector GEMM.
// Block = 256 threads (4 waves), 32 nodes/block staged in LDS.
// Wave w computes nodes 8w..8w+7; lane owns output features 2*lane,2*lane+1.
// ---------------------------------------------------------------------------
__global__ __launch_bounds__(256)
void gemm_G_kernel(const float* __restrict__ h, const float* __restrict__ WT,
                   unsigned short* __restrict__ G) {
    const int block0 = blockIdx.x * GB_NODES;
    __shared__ float hs[GB_NODES][D];  // 16 KB

    const int tid = threadIdx.x;
    const float4* hsrc = reinterpret_cast<const float4*>(h + (size_t)block0 * D);
    float4* hdst = reinterpret_cast<float4*>(&hs[0][0]);
    for (int i = tid; i < GB_NODES * D / 4; i += 256) hdst[i] = hsrc[i];
    __syncthreads();

    const int wave = tid >> 6;
    const int lane = tid & 63;
    const int nb = wave * 8;

    float2 acc[8];
#pragma unroll
    for (int n = 0; n < 8; ++n) acc[n] = make_float2(0.f, 0.f);

    for (int k = 0; k < D; ++k) {
        const float2 w = *reinterpret_cast<const float2*>(WT + k * D + lane * 2);
#pragma unroll
        for (int n = 0; n < 8; ++n) {
            const float hv = hs[nb + n][k];  // broadcast
            acc[n].x += hv * w.x;
            acc[n].y += hv * w.y;
        }
    }

#pragma unroll
    for (int n = 0; n < 8; ++n) {
        const int node = block0 + nb + n;
        __hip_bfloat162 p;
        p.x = __float2bfloat16(acc[n].x);
        p.y = __float2bfloat16(acc[n].y);
        *reinterpret_cast<__hip_bfloat162*>(G + (size_t)node * D + lane * 2) = p;
    }
}

// ---------------------------------------------------------------------------
// Kernel 4: out = relu(S @ G + b). One wave per node.
// Wave split into 4 groups of 16 lanes; group g handles edges e = start+g,
// stride 4; lane (within group) il owns features il*8..il*8+7 (16 B bf16).
// 4 edges in flight per group = 16 per wave. Cross-group combine: shfl_xor.
// ---------------------------------------------------------------------------
__device__ __forceinline__ void acc_bf8(float* acc, float v, const uint4& g) {
    const unsigned u[4] = {g.x, g.y, g.z, g.w};
#pragma unroll
    for (int i = 0; i < 4; ++i) {
        const float lo = __uint_as_float(u[i] << 16);
        const float hi = __uint_as_float(u[i] & 0xffff0000u);
        acc[2 * i]     += v * lo;
        acc[2 * i + 1] += v * hi;
    }
}

__global__ __launch_bounds__(64)
void gconv_gather_kernel(const int* __restrict__ cols,
                         const float* __restrict__ vals,
                         const unsigned short* __restrict__ G,
                         const float* __restrict__ b,
                         const int* __restrict__ row_ptr,
                         float* __restrict__ out) {
    const int node  = blockIdx.x;
    const int lane  = threadIdx.x;
    const int group = lane >> 4;
    const int il    = lane & 15;

    const int start = row_ptr[node];
    const int end   = row_ptr[node + 1];

    float acc[8];
#pragma unroll
    for (int j = 0; j < 8; ++j) acc[j] = 0.f;

    int e = start + group;
    for (; e + 12 < end; e += 16) {
        const int c0 = cols[e];
        const int c1 = cols[e + 4];
        const int c2 = cols[e + 8];
        const int c3 = cols[e + 12];
        const float v0 = vals[e];
        const float v1 = vals[e + 4];
        const float v2 = vals[e + 8];
        const float v3 = vals[e + 12];
        const uint4 g0 = *reinterpret_cast<const uint4*>(G + (size_t)c0 * D + il * 8);
        const uint4 g1 = *reinterpret_cast<const uint4*>(G + (size_t)c1 * D + il * 8);
        const uint4 g2 = *reinterpret_cast<const uint4*>(G + (size_t)c2 * D + il * 8);
        const uint4 g3 = *reinterpret_cast<const uint4*>(G + (size_t)c3 * D + il * 8);
        acc_bf8(acc, v0, g0);
        acc_bf8(acc, v1, g1);
        acc_bf8(acc, v2, g2);
        acc_bf8(acc, v3, g3);
    }
    for (; e < end; e += 4) {
        const int   c = cols[e];
        const float v = vals[e];
        const uint4 g = *reinterpret_cast<const uint4*>(G + (size_t)c * D + il * 8);
        acc_bf8(acc, v, g);
    }

#pragma unroll
    for (int j = 0; j < 8; ++j) {
        acc[j] += __shfl_xor(acc[j], 16);
        acc[j] += __shfl_xor(acc[j], 32);
    }

    if (group < 2) {
        const int fo = il * 8 + group * 4;
        const float4 bb = *reinterpret_cast<const float4*>(b + fo);
        float4 r;
        r.x = acc[group * 4 + 0] + bb.x;
        r.y = acc[group * 4 + 1] + bb.y;
        r.z = acc[group * 4 + 2] + bb.z;
        r.w = acc[group * 4 + 3] + bb.w;
        r.x = r.x > 0.f ? r.x : 0.f;
        r.y = r.y > 0.f ? r.y : 0.f;
        r.z = r.z > 0.f ? r.z : 0.f;
        r.w = r.w > 0.f ? r.w : 0.f;
        *reinterpret_cast<float4*>(out + (size_t)node * D + fo) = r;
    }
}

// ---------------------------------------------------------------------------
// Fallback (R2 path) if workspace is too small for G.
// ---------------------------------------------------------------------------
__global__ __launch_bounds__(64)
void gconv_fused_kernel(const int* __restrict__ cols,
                        const float* __restrict__ vals,
                        const float* __restrict__ h,
                        const float* __restrict__ WT,
                        const float* __restrict__ b,
                        const int* __restrict__ row_ptr,
                        float* __restrict__ out) {
    const int node = blockIdx.x;
    const int lane = threadIdx.x;
    const int half = lane >> 5;
    const int fl   = lane & 31;

    const int start = row_ptr[node];
    const int end   = row_ptr[node + 1];

    float4 acc = make_float4(0.f, 0.f, 0.f, 0.f);
    int e = start + half;
    for (; e + 6 < end; e += 8) {
        const int c0 = cols[e];
        const int c1 = cols[e + 2];
        const int c2 = cols[e + 4];
        const int c3 = cols[e + 6];
        const float v0 = vals[e];
        const float v1 = vals[e + 2];
        const float v2 = vals[e + 4];
        const float v3 = vals[e + 6];
        const float4 h0 = *reinterpret_cast<const float4*>(h + (size_t)c0 * D + fl * 4);
        const float4 h1 = *reinterpret_cast<const float4*>(h + (size_t)c1 * D + fl * 4);
        const float4 h2 = *reinterpret_cast<const float4*>(h + (size_t)c2 * D + fl * 4);
        const float4 h3 = *reinterpret_cast<const float4*>(h + (size_t)c3 * D + fl * 4);
        acc.x += v0 * h0.x; acc.y += v0 * h0.y; acc.z += v0 * h0.z; acc.w += v0 * h0.w;
        acc.x += v1 * h1.x; acc.y += v1 * h1.y; acc.z += v1 * h1.z; acc.w += v1 * h1.w;
        acc.x += v2 * h2.x; acc.y += v2 * h2.y; acc.z += v2 * h2.z; acc.w += v2 * h2.w;
        acc.x += v3 * h3.x; acc.y += v3 * h3.y; acc.z += v3 * h3.z; acc.w += v3 * h3.w;
    }
    for (; e < end; e += 2) {
        const int   c = cols[e];
        const float v = vals[e];
        const float4 hv = *reinterpret_cast<const float4*>(h + (size_t)c * D + fl * 4);
        acc.x += v * hv.x; acc.y += v * hv.y; acc.z += v * hv.z; acc.w += v * hv.w;
    }

    acc.x += __shfl_xor(acc.x, 32);
    acc.y += __shfl_xor(acc.y, 32);
    acc.z += __shfl_xor(acc.z, 32);
    acc.w += __shfl_xor(acc.w, 32);

    __shared__ float agg[D];
    if (half == 0) *reinterpret_cast<float4*>(agg + fl * 4) = acc;
    __syncthreads();

    float4 o = make_float4(0.f, 0.f, 0.f, 0.f);
    const int k0 = half * 64;
#pragma unroll 8
    for (int kk = 0; kk < 64; ++kk) {
        const int k = k0 + kk;
        const float a = agg[k];
        const float4 w = *reinterpret_cast<const float4*>(WT + k * D + fl * 4);
        o.x += a * w.x; o.y += a * w.y; o.z += a * w.z; o.w += a * w.w;
    }
    o.x += __shfl_xor(o.x, 32);
    o.y += __shfl_xor(o.y, 32);
    o.z += __shfl_xor(o.z, 32);
    o.w += __shfl_xor(o.w, 32);

    if (half == 0) {
        const float4 bb = *reinterpret_cast<const float4*>(b + fl * 4);
        float4 res;
        res.x = o.x + bb.x; res.y = o.y + bb.y;
        res.z = o.z + bb.z; res.w = o.w + bb.w;
        res.x = res.x > 0.f ? res.x : 0.f;
        res.y = res.y > 0.f ? res.y : 0.f;
        res.z = res.z > 0.f ? res.z : 0.f;
        res.w = res.w > 0.f ? res.w : 0.f;
        *reinterpret_cast<float4*>(out + (size_t)node * D + fl * 4) = res;
    }
}

// ---------------------------------------------------------------------------
extern "C" void kernel_launch(void* const* d_in, const int* in_sizes, int n_in,
                              void* d_out, int out_size, void* d_ws,
                              size_t ws_size, hipStream_t stream) {
    const int*   edge_rows = (const int*)d_in[0];
    const int*   edge_cols = (const int*)d_in[1];
    const float* edge_vals = (const float*)d_in[2];
    const float* h         = (const float*)d_in[3];
    const float* W         = (const float*)d_in[4];
    const float* b         = (const float*)d_in[5];
    float*       out       = (float*)d_out;

    const int n_edges = in_sizes[0];

    // workspace layout
    const size_t WT_OFF = 0;                      // 64 KB fp32 WT
    const size_t RP_OFF = 64 * 1024;              // row_ptr: (N+1) ints
    const size_t G_OFF  = 64 * 1024 + 512 * 1024; // bf16 G: N*D*2 bytes
    const size_t need   = G_OFF + (size_t)N_NODES * D * 2;

    float* WT      = (float*)((char*)d_ws + WT_OFF);
    int*   row_ptr = (int*)((char*)d_ws + RP_OFF);

    transpose_W_kernel<<<D, D, 0, stream>>>(W, WT);

    const int rp_threads = 256;
    const int rp_blocks  = (N_NODES + 1 + rp_threads - 1) / rp_threads;
    build_rowptr_kernel<<<rp_blocks, rp_threads, 0, stream>>>(edge_rows,
                                                              row_ptr, n_edges);

    if (ws_size >= need) {
        unsigned short* G = (unsigned short*)((char*)d_ws + G_OFF);
        gemm_G_kernel<<<N_NODES / GB_NODES, 256, 0, stream>>>(h, WT, G);
        gconv_gather_kernel<<<N_NODES, 64, 0, stream>>>(edge_cols, edge_vals, G,
                                                        b, row_ptr, out);
    } else {
        gconv_fused_kernel<<<N_NODES, 64, 0, stream>>>(edge_cols, edge_vals, h,
                                                       WT, b, row_ptr, out);
    }
}

// Round 4
// 153.216 us; speedup vs baseline: 3.0495x; 1.2129x over previous
//
#include <hip/hip_runtime.h>

#define N_NODES 100000
#define D 128

typedef unsigned short ushort_t;
typedef __attribute__((ext_vector_type(8))) short short8;
typedef __attribute__((ext_vector_type(4))) float f32x4;

// round-to-nearest-even f32 -> bf16 bits (finite inputs)
__device__ __forceinline__ unsigned f2bf(float x) {
    unsigned u = __float_as_uint(x);
    return (u + 0x7fffu + ((u >> 16) & 1u)) >> 16;
}

// ---------------------------------------------------------------------------
// Kernel 1: W -> MFMA A-fragment-ordered bf16 (Wfrag).
// For mfma_f32_16x16x32_bf16, A-frag: lane l holds row (l&15), k = (l>>4)*8+i.
// A-matrix here is W's (jt,kt) tile: A[j][k] = W[jt*16+j][kt*32+k].
// Layout: Wfrag[((jt*4+kt)*64 + l)*8 + i]  (16B contiguous per lane).
// ---------------------------------------------------------------------------
__global__ __launch_bounds__(64)
void build_wfrag_kernel(const float* __restrict__ W,
                        ushort_t* __restrict__ Wfrag) {
    const int t  = blockIdx.x;      // 0..31 = jt*4 + kt
    const int jt = t >> 2, kt = t & 3;
    const int l  = threadIdx.x;
    const float* src = W + (size_t)(jt * 16 + (l & 15)) * D + kt * 32 + (l >> 4) * 8;
    const float4 p0 = *reinterpret_cast<const float4*>(src);
    const float4 p1 = *reinterpret_cast<const float4*>(src + 4);
    uint4 o;
    o.x = f2bf(p0.x) | (f2bf(p0.y) << 16);
    o.y = f2bf(p0.z) | (f2bf(p0.w) << 16);
    o.z = f2bf(p1.x) | (f2bf(p1.y) << 16);
    o.w = f2bf(p1.z) | (f2bf(p1.w) << 16);
    *reinterpret_cast<uint4*>(Wfrag + ((size_t)t * 64 + l) * 8) = o;
}

// ---------------------------------------------------------------------------
// Kernel 2: row_ptr[i] = lower_bound(edge_rows, i)
// ---------------------------------------------------------------------------
__global__ void build_rowptr_kernel(const int* __restrict__ rows,
                                    int* __restrict__ row_ptr, int n_edges) {
    int i = blockIdx.x * blockDim.x + threadIdx.x;
    if (i > N_NODES) return;
    int lo = 0, hi = n_edges;
    while (lo < hi) {
        int mid = (lo + hi) >> 1;
        if (rows[mid] < i) lo = mid + 1; else hi = mid;
    }
    row_ptr[i] = lo;
}

// ---------------------------------------------------------------------------
// Kernel 3: G = bf16(H @ W^T) via MFMA. Computes G^T tiles: D = Wtile * h^T.
//   A = W (16j x 32k) frag from Wfrag (16B/lane loads),
//   B = h  (32k x 16n) frag: lane l reads h[n0+(l&15)][kt*32+(l>>4)*8 ..+7].
//   C: lane l, reg r -> j = jt*16 + (l>>4)*4 + r, node = n0 + (l&15)
//      -> 4 consecutive j per lane -> packed 8B store into row-major G.
// One wave per 16-node tile, 4 waves/block.
// ---------------------------------------------------------------------------
__global__ __launch_bounds__(256)
void gemm_G_kernel(const float* __restrict__ h,
                   const ushort_t* __restrict__ Wfrag,
                   ushort_t* __restrict__ G) {
    const int wave = threadIdx.x >> 6;
    const int l    = threadIdx.x & 63;
    const int tile = blockIdx.x * 4 + wave;
    if (tile >= N_NODES / 16) return;
    const int n0   = tile * 16;
    const int lrow = l & 15;     // node-within-tile (B col / C col)
    const int lk   = l >> 4;     // k-chunk

    // Load + convert the 4 h (B) fragments, reused across all jt.
    union { short8 v; ushort_t u[8]; } bfrag[4];
    const float* hp = h + (size_t)(n0 + lrow) * D + lk * 8;
#pragma unroll
    for (int kt = 0; kt < 4; ++kt) {
        const float4 q0 = *reinterpret_cast<const float4*>(hp + kt * 32);
        const float4 q1 = *reinterpret_cast<const float4*>(hp + kt * 32 + 4);
        bfrag[kt].u[0] = (ushort_t)f2bf(q0.x);
        bfrag[kt].u[1] = (ushort_t)f2bf(q0.y);
        bfrag[kt].u[2] = (ushort_t)f2bf(q0.z);
        bfrag[kt].u[3] = (ushort_t)f2bf(q0.w);
        bfrag[kt].u[4] = (ushort_t)f2bf(q1.x);
        bfrag[kt].u[5] = (ushort_t)f2bf(q1.y);
        bfrag[kt].u[6] = (ushort_t)f2bf(q1.z);
        bfrag[kt].u[7] = (ushort_t)f2bf(q1.w);
    }

    const uint4* wf = reinterpret_cast<const uint4*>(Wfrag) + l;
#pragma unroll
    for (int jt = 0; jt < 8; ++jt) {
        f32x4 acc = {0.f, 0.f, 0.f, 0.f};
#pragma unroll
        for (int kt = 0; kt < 4; ++kt) {
            union { uint4 q; short8 v; } af;
            af.q = wf[(jt * 4 + kt) * 64];
            acc = __builtin_amdgcn_mfma_f32_16x16x32_bf16(af.v, bfrag[kt].v,
                                                          acc, 0, 0, 0);
        }
        uint2 o;
        o.x = f2bf(acc[0]) | (f2bf(acc[1]) << 16);
        o.y = f2bf(acc[2]) | (f2bf(acc[3]) << 16);
        *reinterpret_cast<uint2*>(G + (size_t)(n0 + lrow) * D + jt * 16 + lk * 4) = o;
    }
}

// ---------------------------------------------------------------------------
// Kernel 4: out = relu(S @ G + b). ONE NODE PER 16-LANE GROUP (4 nodes/wave).
// Group owns the full 256B bf16 row (lane il holds feats il*8..il*8+7);
// walks its own contiguous edge range with depth-4 unroll; no cross-lane
// combine. cols/vals loads fold to base+immediate offsets.
// ---------------------------------------------------------------------------
__device__ __forceinline__ void acc8(float2& a0, float2& a1, float2& a2,
                                     float2& a3, float v, uint4 g) {
    a0.x += v * __uint_as_float(g.x << 16);
    a0.y += v * __uint_as_float(g.x & 0xffff0000u);
    a1.x += v * __uint_as_float(g.y << 16);
    a1.y += v * __uint_as_float(g.y & 0xffff0000u);
    a2.x += v * __uint_as_float(g.z << 16);
    a2.y += v * __uint_as_float(g.z & 0xffff0000u);
    a3.x += v * __uint_as_float(g.w << 16);
    a3.y += v * __uint_as_float(g.w & 0xffff0000u);
}

__global__ __launch_bounds__(256)
void gconv_gather_kernel(const int* __restrict__ cols,
                         const float* __restrict__ vals,
                         const ushort_t* __restrict__ G,
                         const float* __restrict__ b,
                         const int* __restrict__ row_ptr,
                         float* __restrict__ out) {
    const int tid  = blockIdx.x * 256 + threadIdx.x;
    const int node = tid >> 4;
    const int il   = tid & 15;

    int e = row_ptr[node];
    const int end = row_ptr[node + 1];
    const ushort_t* gp = G + il * 8;

    float2 a0 = make_float2(0.f, 0.f), a1 = make_float2(0.f, 0.f);
    float2 a2 = make_float2(0.f, 0.f), a3 = make_float2(0.f, 0.f);

    for (; e + 3 < end; e += 4) {
        const int c0 = cols[e];
        const int c1 = cols[e + 1];
        const int c2 = cols[e + 2];
        const int c3 = cols[e + 3];
        const float v0 = vals[e];
        const float v1 = vals[e + 1];
        const float v2 = vals[e + 2];
        const float v3 = vals[e + 3];
        const uint4 g0 = *reinterpret_cast<const uint4*>(gp + (size_t)c0 * D);
        const uint4 g1 = *reinterpret_cast<const uint4*>(gp + (size_t)c1 * D);
        const uint4 g2 = *reinterpret_cast<const uint4*>(gp + (size_t)c2 * D);
        const uint4 g3 = *reinterpret_cast<const uint4*>(gp + (size_t)c3 * D);
        acc8(a0, a1, a2, a3, v0, g0);
        acc8(a0, a1, a2, a3, v1, g1);
        acc8(a0, a1, a2, a3, v2, g2);
        acc8(a0, a1, a2, a3, v3, g3);
    }
    for (; e < end; ++e) {
        const int   c = cols[e];
        const float v = vals[e];
        const uint4 g = *reinterpret_cast<const uint4*>(gp + (size_t)c * D);
        acc8(a0, a1, a2, a3, v, g);
    }

    const float4 b0 = *reinterpret_cast<const float4*>(b + il * 8);
    const float4 b1 = *reinterpret_cast<const float4*>(b + il * 8 + 4);
    float4 r0, r1;
    r0.x = a0.x + b0.x; r0.y = a0.y + b0.y;
    r0.z = a1.x + b0.z; r0.w = a1.y + b0.w;
    r1.x = a2.x + b1.x; r1.y = a2.y + b1.y;
    r1.z = a3.x + b1.z; r1.w = a3.y + b1.w;
    r0.x = r0.x > 0.f ? r0.x : 0.f;
    r0.y = r0.y > 0.f ? r0.y : 0.f;
    r0.z = r0.z > 0.f ? r0.z : 0.f;
    r0.w = r0.w > 0.f ? r0.w : 0.f;
    r1.x = r1.x > 0.f ? r1.x : 0.f;
    r1.y = r1.y > 0.f ? r1.y : 0.f;
    r1.z = r1.z > 0.f ? r1.z : 0.f;
    r1.w = r1.w > 0.f ? r1.w : 0.f;
    float* op = out + (size_t)node * D + il * 8;
    *reinterpret_cast<float4*>(op)     = r0;
    *reinterpret_cast<float4*>(op + 4) = r1;
}

// ---------------------------------------------------------------------------
extern "C" void kernel_launch(void* const* d_in, const int* in_sizes, int n_in,
                              void* d_out, int out_size, void* d_ws,
                              size_t ws_size, hipStream_t stream) {
    const int*   edge_rows = (const int*)d_in[0];
    const int*   edge_cols = (const int*)d_in[1];
    const float* edge_vals = (const float*)d_in[2];
    const float* h         = (const float*)d_in[3];
    const float* W         = (const float*)d_in[4];
    const float* b         = (const float*)d_in[5];
    float*       out       = (float*)d_out;

    const int n_edges = in_sizes[0];

    // workspace layout: [Wfrag 32KB][pad to 64KB][row_ptr 512KB][G 25.6MB]
    ushort_t* Wfrag   = (ushort_t*)d_ws;
    int*      row_ptr = (int*)((char*)d_ws + 64 * 1024);
    ushort_t* G       = (ushort_t*)((char*)d_ws + 64 * 1024 + 512 * 1024);

    build_wfrag_kernel<<<32, 64, 0, stream>>>(W, Wfrag);

    const int rp_threads = 256;
    const int rp_blocks  = (N_NODES + 1 + rp_threads - 1) / rp_threads;
    build_rowptr_kernel<<<rp_blocks, rp_threads, 0, stream>>>(edge_rows,
                                                              row_ptr, n_edges);

    const int n_tiles = N_NODES / 16;                 // 6250
    gemm_G_kernel<<<(n_tiles + 3) / 4, 256, 0, stream>>>(h, Wfrag, G);

    gconv_gather_kernel<<<N_NODES * 16 / 256, 256, 0, stream>>>(
        edge_cols, edge_vals, G, b, row_ptr, out);
}